// Round 10
// baseline (302.315 us; speedup 1.0000x reference)
//
#include <hip/hip_runtime.h>

#define B_    8
#define V_    50000
#define KNB   9
#define CIN_  64
#define COUT_ 128
#define VOUT_ 12500
#define NNZ_  37500
#define KTOT  576      // KNB*CIN_
#define M_    400000   // B_*V_
#define NWG   3125     // M_/128

typedef short bf16x8 __attribute__((ext_vector_type(8)));
typedef float f32x4  __attribute__((ext_vector_type(4)));

__device__ __forceinline__ unsigned short f2bf(float f) {
  unsigned u = __float_as_uint(f);
  u += 0x7fffu + ((u >> 16) & 1u);          // RNE
  return (unsigned short)(u >> 16);
}
__device__ __forceinline__ unsigned pack2(float lo, float hi) {
  return (unsigned)f2bf(lo) | ((unsigned)f2bf(hi) << 16);
}
__device__ __forceinline__ float bf2f(unsigned short u) {
  return __uint_as_float((unsigned)u << 16);
}

// Fused prep: [0,36) W->frag-major bf16; [36,183) pool bucket-fill (atomic cursor).
// convert_x is GONE (R10): the gemm gathers fp32 x directly and converts in-register.
#define PREP_WBLK 36
#define PREP_FBLK 147
__global__ __launch_bounds__(256) void prep(const float* __restrict__ w,
                                            unsigned short* __restrict__ wfr,
                                            const int* __restrict__ dr,
                                            const int* __restrict__ dc,
                                            const float* __restrict__ dd,
                                            int* __restrict__ cursor,
                                            int2* __restrict__ elist) {
  const int bid = blockIdx.x;
  if (bid < PREP_WBLK) {
    // W -> MFMA-fragment-major: chunk i holds, for lane=i&63, n=(i>>6)&3,
    // wc=(i>>8)&1, ks=(i>>9)&1, t=i>>10:
    //   W[col=wc*64+n*16+(lane&15)][k=t*64+ks*32+(lane>>4)*8 .. +8]
    int i = bid * 256 + threadIdx.x;        // 0..9215
    int lane = i & 63, n = (i >> 6) & 3, wc = (i >> 8) & 1, ks = (i >> 9) & 1, t = i >> 10;
    int col = wc * 64 + n * 16 + (lane & 15);
    int k0 = t * 64 + ks * 32 + (lane >> 4) * 8;
    const float* src = w + (size_t)col * KTOT + k0;
    float4 f0 = reinterpret_cast<const float4*>(src)[0];
    float4 f1 = reinterpret_cast<const float4*>(src)[1];
    uint4 o;
    o.x = pack2(f0.x, f0.y);
    o.y = pack2(f0.z, f0.w);
    o.z = pack2(f1.x, f1.y);
    o.w = pack2(f1.z, f1.w);
    reinterpret_cast<uint4*>(wfr)[i] = o;
  } else {
    int e = (bid - PREP_WBLK) * 256 + threadIdx.x;
    if (e < NNZ_) {
      int r = dr[e];
      int slot = atomicAdd(&cursor[r], 1);
      if (slot < 32) elist[r * 32 + slot] = make_int2(dc[e], __float_as_int(dd[e]));
    }
  }
}

// h = elu(gather(x) @ W^T + bias). 128x128 tile, 4 waves (2x2 of 64x64), BK=64.
// R10 structure: direct fp32 gather -> registers (8 x dwordx4 per thread, issued at
// iter START for tile t+1) -> fp32->bf16 convert -> swizzled ds_write at iter END
// (T14 issue-early/write-late: loads in flight across the whole compute phase).
// All dependencies are compiler-tracked (no global_load_lds, no manual vmcnt —
// eliminates R9's latent vmcnt race). One __syncthreads per K-step; at the barrier
// nothing is left in the VMEM queue, so its implicit drain costs nothing.
// LDS: A 2x16KB + spc 4.6KB = 36.5KB. launch_bounds(256,3): VGPR cap ~170
// (stage regs 32 + acc 64 + B 16 + af 16 + addr), no spill (R7 lesson).
struct GemmSM { char A[2][16384]; int spc[128 * KNB]; };

__global__ __launch_bounds__(256, 3) void spiral_gemm(
    const float* __restrict__ x, const unsigned short* __restrict__ wfr,
    const float* __restrict__ bias, const int* __restrict__ sp,
    unsigned short* __restrict__ hbf)
{
  __shared__ GemmSM smv;
  GemmSM* sm = &smv;

  // ---- bijective XCD swizzle (nwg=3125: q=390, r=5)
  const int q_ = NWG / 8, r_ = NWG % 8;
  const int xcd = blockIdx.x & 7, pos = blockIdx.x >> 3;
  const int nbid = (xcd < r_) ? xcd * (q_ + 1) + pos
                              : r_ * (q_ + 1) + (xcd - r_) * q_ + pos;

  const int tid  = threadIdx.x;
  const int m0   = nbid * 128;
  const int wave = tid >> 6;
  const int lane = tid & 63;

  // ---- cache all 1152 spiral indices for this tile in LDS (lgkm domain)
  for (int i = tid; i < 128 * KNB; i += 256) {
    int row = i / KNB, j = i - row * KNB;
    int m = m0 + row;
    int b = m / V_;
    int v = m - b * V_;
    sm->spc[i] = sp[v * KNB + j];
  }

  // ---- staging geometry: 2 threads per row; each moves 32 fp32 -> 64B bf16
  const int srow  = tid >> 1;                 // 0..127
  const int shalf = tid & 1;                  // half of the 64-elem row
  const int sswz  = (srow & 7) << 4;
  {
  }
  int sb = (m0 + srow) / V_;
  const float* xrow_base = x + (size_t)sb * (V_ * CIN_) + shalf * 32;

  // ---- compute geometry
  const int wr = wave >> 1, wc = wave & 1;
  const int lr = lane & 15, lg = lane >> 4;
  const bf16x8* wbase = (const bf16x8*)wfr + wc * 256 + lane;   // +((t*2+ks)*512 + n*64)

  f32x4 acc[4][4];
  #pragma unroll
  for (int i = 0; i < 4; ++i)
    #pragma unroll
    for (int j = 0; j < 4; ++j)
      acc[i][j] = (f32x4){0.f, 0.f, 0.f, 0.f};

  __syncthreads();     // spc visible

  float4 sreg[8];
  auto loadStage = [&](int t) {
    int idx = sm->spc[srow * KNB + t];
    const float4* src = reinterpret_cast<const float4*>(xrow_base + (size_t)idx * CIN_);
    #pragma unroll
    for (int i = 0; i < 8; ++i) sreg[i] = src[i];
  };
  auto writeStage = [&](int slot) {
    char* Ab = sm->A[slot] + srow * 128;
    #pragma unroll
    for (int c = 0; c < 4; ++c) {
      float4 a = sreg[2 * c], b4 = sreg[2 * c + 1];
      uint4 o;
      o.x = pack2(a.x, a.y);
      o.y = pack2(a.z, a.w);
      o.z = pack2(b4.x, b4.y);
      o.w = pack2(b4.z, b4.w);
      *reinterpret_cast<uint4*>(Ab + ((shalf * 64 + c * 16) ^ sswz)) = o;
    }
  };

  // ---- prologue: stage A(0)
  loadStage(0);
  writeStage(0);
  __syncthreads();

  // ---- main loop: issue loads(t+1) EARLY, compute(t), write(t+1) LATE, barrier.
  #pragma unroll 1
  for (int t = 0; t < KNB; ++t) {
    if (t + 1 < KNB) loadStage(t + 1);          // 8 dwordx4 in flight across compute
    const char* Ab = sm->A[t & 1];
    #pragma unroll
    for (int ks = 0; ks < 2; ++ks) {
      bf16x8 bk[4];                             // B(t,ks) JIT from L1/L2
      #pragma unroll
      for (int n = 0; n < 4; ++n)
        bk[n] = wbase[(t * 2 + ks) * 512 + n * 64];
      const int kb = ks * 64 + lg * 16;
      bf16x8 af[4];
      #pragma unroll
      for (int m = 0; m < 4; ++m) {
        int row = wr * 64 + m * 16 + lr;
        af[m] = *reinterpret_cast<const bf16x8*>(Ab + row * 128 + (kb ^ ((row & 7) << 4)));
      }
      __builtin_amdgcn_s_setprio(1);
      #pragma unroll
      for (int m = 0; m < 4; ++m)
        #pragma unroll
        for (int n = 0; n < 4; ++n)
          acc[m][n] = __builtin_amdgcn_mfma_f32_16x16x32_bf16(af[m], bk[n], acc[m][n], 0, 0, 0);
      __builtin_amdgcn_s_setprio(0);
    }
    if (t + 1 < KNB) writeStage((t + 1) & 1);   // compiler waits sreg vmcnt here
    __syncthreads();                             // queue is empty: drain is free
  }

  // ---- epilogue: bias + ELU -> bf16 into swizzled hs over A[0..1] (32KB),
  //      then coalesced 16B global stores.
  char* hsb = (char*)sm;
  #pragma unroll
  for (int n = 0; n < 4; ++n) {
    const int c = wc * 64 + n * 16 + lr;
    const float bv = bias[c];
    #pragma unroll
    for (int m = 0; m < 4; ++m) {
      const int row0 = wr * 64 + m * 16 + lg * 4;
      #pragma unroll
      for (int j = 0; j < 4; ++j) {
        const int row = row0 + j;
        float vv = acc[m][n][j] + bv;
        vv = vv > 0.f ? vv : (__expf(vv) - 1.f);
        *reinterpret_cast<unsigned short*>(
            hsb + row * 256 + ((c * 2) ^ ((row & 7) << 4))) = f2bf(vv);
      }
    }
  }
  __syncthreads();
  const int r2 = tid >> 1, hf = tid & 1;
  uint4* drow = reinterpret_cast<uint4*>(hbf + (size_t)(m0 + r2) * COUT_ + hf * 64);
  #pragma unroll
  for (int u = 0; u < 8; ++u) {
    int cb = hf * 128 + u * 16;
    drow[u] = *reinterpret_cast<const uint4*>(hsb + r2 * 256 + (cb ^ ((r2 & 7) << 4)));
  }
}

// One block per output row; 8 b-groups x 32 lanes; bucketed entries (cap 32).
__global__ __launch_bounds__(256) void pool_rows(const unsigned short* __restrict__ hbf,
                                                 const int* __restrict__ cursor,
                                                 const int2* __restrict__ elist,
                                                 float* __restrict__ out) {
  const int row = blockIdx.x;
  const int bg = threadIdx.x >> 5;     // batch 0..7
  const int lc = threadIdx.x & 31;     // c-quad 0..31
  int cnt = cursor[row];
  cnt = cnt < 32 ? cnt : 32;
  const unsigned short* hb = hbf + (size_t)bg * (V_ * COUT_) + lc * 4;
  float4 acc = {0.f, 0.f, 0.f, 0.f};
  for (int e = 0; e < cnt; ++e) {
    int2 en = elist[row * 32 + e];
    float d = __int_as_float(en.y);
    ushort4 v = *reinterpret_cast<const ushort4*>(hb + (size_t)en.x * COUT_);
    acc.x += d * bf2f(v.x);
    acc.y += d * bf2f(v.y);
    acc.z += d * bf2f(v.z);
    acc.w += d * bf2f(v.w);
  }
  *reinterpret_cast<float4*>(out + ((size_t)bg * VOUT_ + row) * COUT_ + lc * 4) = acc;
}

extern "C" void kernel_launch(void* const* d_in, const int* in_sizes, int n_in,
                              void* d_out, int out_size, void* d_ws, size_t ws_size,
                              hipStream_t stream) {
  const float* x    = (const float*)d_in[0];
  const float* w    = (const float*)d_in[1];
  const float* bias = (const float*)d_in[2];
  const int*   sp   = (const int*)d_in[3];
  const int*   dr   = (const int*)d_in[4];
  const int*   dc   = (const int*)d_in[5];
  const float* dd   = (const float*)d_in[6];
  float* out = (float*)d_out;

  char* ws = (char*)d_ws;
  unsigned short* wfr = (unsigned short*)ws;                       // 147,456 B (frag-major)
  unsigned short* hbf = (unsigned short*)(ws + 147456);            // 102,400,000 B
  int*  cursor  = (int*) (ws + 102547456);                         // 50,000 B
  int2* elist   = (int2*)(ws + 102597456);                         // 3,200,000 B

  hipMemsetAsync(cursor, 0, VOUT_ * sizeof(int), stream);
  prep<<<PREP_WBLK + PREP_FBLK, 256, 0, stream>>>(w, wfr, dr, dc, dd, cursor, elist);
  spiral_gemm<<<NWG, 256, 0, stream>>>(x, wfr, bias, sp, hbf);
  pool_rows<<<VOUT_, 256, 0, stream>>>(hbf, cursor, elist, out);
}

// Round 11
// 201.490 us; speedup vs baseline: 1.5004x; 1.5004x over previous
//
#include <hip/hip_runtime.h>

#define B_    8
#define V_    50000
#define KNB   9
#define CIN_  64
#define COUT_ 128
#define VOUT_ 12500
#define NNZ_  37500
#define KTOT  576      // KNB*CIN_
#define M_    400000   // B_*V_
#define WR    64       // rows per wave-tile
#define NWG2  12500    // (M_/WR) * 2 col-halves

typedef short bf16x8 __attribute__((ext_vector_type(8)));
typedef float f32x4  __attribute__((ext_vector_type(4)));

__device__ __forceinline__ unsigned short f2bf(float f) {
  unsigned u = __float_as_uint(f);
  u += 0x7fffu + ((u >> 16) & 1u);          // RNE
  return (unsigned short)(u >> 16);
}
__device__ __forceinline__ unsigned pack2(float lo, float hi) {
  return (unsigned)f2bf(lo) | ((unsigned)f2bf(hi) << 16);
}
__device__ __forceinline__ float bf2f(unsigned short u) {
  return __uint_as_float((unsigned)u << 16);
}

// Fused prep: [0,36) W->frag-major bf16; [36,183) pool bucket-fill; [183,2231)
// convert x fp32->bf16 (grid-stride). (R10's fp32-direct gather was refuted:
// 2x gather bytes + lost L3 residency; bf16 xbf is the right trade.)
#define PREP_WBLK 36
#define PREP_FBLK 147
#define PREP_XBLK 2048
__global__ __launch_bounds__(256) void prep(const float* __restrict__ w,
                                            unsigned short* __restrict__ wfr,
                                            const float* __restrict__ x,
                                            unsigned short* __restrict__ xbf,
                                            const int* __restrict__ dr,
                                            const int* __restrict__ dc,
                                            const float* __restrict__ dd,
                                            int* __restrict__ cursor,
                                            int2* __restrict__ elist) {
  const int bid = blockIdx.x;
  if (bid < PREP_WBLK) {
    // W -> MFMA-fragment-major: chunk i holds, for lane=i&63, n=(i>>6)&3,
    // wc=(i>>8)&1, ks=(i>>9)&1, t=i>>10:
    //   W[col=wc*64+n*16+(lane&15)][k=t*64+ks*32+(lane>>4)*8 .. +8]
    int i = bid * 256 + threadIdx.x;        // 0..9215
    int lane = i & 63, n = (i >> 6) & 3, wc = (i >> 8) & 1, ks = (i >> 9) & 1, t = i >> 10;
    int col = wc * 64 + n * 16 + (lane & 15);
    int k0 = t * 64 + ks * 32 + (lane >> 4) * 8;
    const float* src = w + (size_t)col * KTOT + k0;
    float4 f0 = reinterpret_cast<const float4*>(src)[0];
    float4 f1 = reinterpret_cast<const float4*>(src)[1];
    uint4 o;
    o.x = pack2(f0.x, f0.y);
    o.y = pack2(f0.z, f0.w);
    o.z = pack2(f1.x, f1.y);
    o.w = pack2(f1.z, f1.w);
    reinterpret_cast<uint4*>(wfr)[i] = o;
  } else if (bid < PREP_WBLK + PREP_FBLK) {
    int e = (bid - PREP_WBLK) * 256 + threadIdx.x;
    if (e < NNZ_) {
      int r = dr[e];
      int slot = atomicAdd(&cursor[r], 1);
      if (slot < 32) elist[r * 32 + slot] = make_int2(dc[e], __float_as_int(dd[e]));
    }
  } else {
    const int nq = B_ * V_ * CIN_ / 4;      // 6.4M float4 quads
    for (int q = (bid - PREP_WBLK - PREP_FBLK) * 256 + threadIdx.x; q < nq;
         q += PREP_XBLK * 256) {
      float4 f = reinterpret_cast<const float4*>(x)[q];
      ushort4 o;
      o.x = f2bf(f.x); o.y = f2bf(f.y); o.z = f2bf(f.z); o.w = f2bf(f.w);
      reinterpret_cast<ushort4*>(xbf)[q] = o;
    }
  }
}

// h = elu(gather(x) @ W^T + bias).
// R11 structure: ONE WAVE per workgroup, 64x64 output tile, ZERO barriers in the
// K-loop. A-fragments are gathered DIRECTLY to registers (one dwordx4 per frag:
// a 16x16x32 A-frag is exactly 16B of a gathered bf16 row at ks*32+lg*8), B-frags
// JIT from the fragment-major wfr (L2-resident). Latency hiding = pure TLP from
// 16 independent waves/CU (no 4-wave barrier coupling — the invariant behind the
// 101-106us plateau of R6/R8/R9). LDS per block: 576-entry combined gather-offset
// table (2.3KB) + 16x68-ushort padded epilogue relay (2.2KB).
// launch_bounds(64,4): unified-file budget 128 regs = acc 64 AGPR + <=64 VGPR
// (af 16 + bk 16 + ofs 4 + addr; R8 proved this layout fits 64).
struct WSM { int spc[WR * KNB]; unsigned short hs[16 * 68]; };

__global__ __launch_bounds__(64, 4) void spiral_gemm(
    const unsigned short* __restrict__ xbf, const unsigned short* __restrict__ wfr,
    const float* __restrict__ bias, const int* __restrict__ sp,
    unsigned short* __restrict__ hbf)
{
  __shared__ WSM sm;

  // ---- bijective XCD swizzle (nwg=12500: q=1562, r=4); then rt/col-half split
  const int q_ = NWG2 / 8, r_ = NWG2 % 8;
  const int xcd = blockIdx.x & 7, pos = blockIdx.x >> 3;
  const int nbid = (xcd < r_) ? xcd * (q_ + 1) + pos
                              : r_ * (q_ + 1) + (xcd - r_) * q_ + pos;
  const int rt = nbid >> 1, wc = nbid & 1;
  const int m0 = rt * WR;

  const int tid = threadIdx.x;                 // 0..63 (one wave)
  const int lr = tid & 15, lg = tid >> 4;

  // ---- combined gather offsets: spc[row*9+t] = b*V*CIN + idx*CIN  (elements)
  for (int i = tid; i < WR * KNB; i += 64) {
    int row = i / KNB, j = i - row * KNB;
    int m = m0 + row;
    int b = m / V_;
    int v = m - b * V_;
    sm.spc[i] = b * (V_ * CIN_) + sp[v * KNB + j] * CIN_;
  }
  __syncthreads();

  const bf16x8* wbase = (const bf16x8*)wfr + wc * 256 + tid;   // +((t*2+ks)*512+n*64)

  f32x4 acc[4][4];
  #pragma unroll
  for (int i = 0; i < 4; ++i)
    #pragma unroll
    for (int j = 0; j < 4; ++j)
      acc[i][j] = (f32x4){0.f, 0.f, 0.f, 0.f};

  // ---- K-loop: no barriers, no LDS staging; compiler-tracked deps only.
  #pragma unroll 1
  for (int t = 0; t < KNB; ++t) {
    int ofs[4];
    #pragma unroll
    for (int m = 0; m < 4; ++m)
      ofs[m] = sm.spc[(m * 16 + lr) * KNB + t];
    #pragma unroll
    for (int ks = 0; ks < 2; ++ks) {
      const int ko = ks * 32 + lg * 8;
      bf16x8 af[4], bk[4];
      #pragma unroll
      for (int m = 0; m < 4; ++m)
        af[m] = *reinterpret_cast<const bf16x8*>(xbf + (unsigned)(ofs[m] + ko));
      #pragma unroll
      for (int n = 0; n < 4; ++n)
        bk[n] = wbase[(t * 2 + ks) * 512 + n * 64];
      __builtin_amdgcn_s_setprio(1);
      #pragma unroll
      for (int m = 0; m < 4; ++m)
        #pragma unroll
        for (int n = 0; n < 4; ++n)
          acc[m][n] = __builtin_amdgcn_mfma_f32_16x16x32_bf16(af[m], bk[n], acc[m][n], 0, 0, 0);
      __builtin_amdgcn_s_setprio(0);
    }
  }

  // ---- epilogue: per m-frag, bias+ELU -> bf16 via padded LDS relay (wave-
  //      synchronous: lgkmcnt fences only, no s_barrier), coalesced 16B stores.
  float bv[4];
  #pragma unroll
  for (int n = 0; n < 4; ++n) bv[n] = bias[wc * 64 + n * 16 + lr];

  #pragma unroll
  for (int m = 0; m < 4; ++m) {
    #pragma unroll
    for (int n = 0; n < 4; ++n)
      #pragma unroll
      for (int j = 0; j < 4; ++j) {
        float vv = acc[m][n][j] + bv[n];
        vv = vv > 0.f ? vv : (__expf(vv) - 1.f);
        sm.hs[(lg * 4 + j) * 68 + n * 16 + lr] = f2bf(vv);
      }
    asm volatile("s_waitcnt lgkmcnt(0)" ::: "memory");
    __builtin_amdgcn_sched_barrier(0);
    #pragma unroll
    for (int p = 0; p < 2; ++p) {
      int row = p * 8 + (tid >> 3);
      int chunk = tid & 7;
      uint4 vvv = *reinterpret_cast<const uint4*>(&sm.hs[row * 68 + chunk * 8]);
      *reinterpret_cast<uint4*>(hbf + (size_t)(m0 + m * 16 + row) * COUT_ +
                                wc * 64 + chunk * 8) = vvv;
    }
    asm volatile("s_waitcnt lgkmcnt(0)" ::: "memory");
    __builtin_amdgcn_sched_barrier(0);
  }
}

// One block per output row; 8 b-groups x 32 lanes; bucketed entries (cap 32).
__global__ __launch_bounds__(256) void pool_rows(const unsigned short* __restrict__ hbf,
                                                 const int* __restrict__ cursor,
                                                 const int2* __restrict__ elist,
                                                 float* __restrict__ out) {
  const int row = blockIdx.x;
  const int bg = threadIdx.x >> 5;     // batch 0..7
  const int lc = threadIdx.x & 31;     // c-quad 0..31
  int cnt = cursor[row];
  cnt = cnt < 32 ? cnt : 32;
  const unsigned short* hb = hbf + (size_t)bg * (V_ * COUT_) + lc * 4;
  float4 acc = {0.f, 0.f, 0.f, 0.f};
  for (int e = 0; e < cnt; ++e) {
    int2 en = elist[row * 32 + e];
    float d = __int_as_float(en.y);
    ushort4 v = *reinterpret_cast<const ushort4*>(hb + (size_t)en.x * COUT_);
    acc.x += d * bf2f(v.x);
    acc.y += d * bf2f(v.y);
    acc.z += d * bf2f(v.z);
    acc.w += d * bf2f(v.w);
  }
  *reinterpret_cast<float4*>(out + ((size_t)bg * VOUT_ + row) * COUT_ + lc * 4) = acc;
}

extern "C" void kernel_launch(void* const* d_in, const int* in_sizes, int n_in,
                              void* d_out, int out_size, void* d_ws, size_t ws_size,
                              hipStream_t stream) {
  const float* x    = (const float*)d_in[0];
  const float* w    = (const float*)d_in[1];
  const float* bias = (const float*)d_in[2];
  const int*   sp   = (const int*)d_in[3];
  const int*   dr   = (const int*)d_in[4];
  const int*   dc   = (const int*)d_in[5];
  const float* dd   = (const float*)d_in[6];
  float* out = (float*)d_out;

  char* ws = (char*)d_ws;
  unsigned short* wfr = (unsigned short*)ws;                       // 147,456 B (frag-major)
  unsigned short* xbf = (unsigned short*)(ws + 147456);            // 51,200,000 B
  unsigned short* hbf = (unsigned short*)(ws + 51347456);          // 102,400,000 B
  int*  cursor  = (int*) (ws + 153747456);                         // 50,000 B
  int2* elist   = (int2*)(ws + 153797456);                         // 3,200,000 B

  hipMemsetAsync(cursor, 0, VOUT_ * sizeof(int), stream);
  prep<<<PREP_WBLK + PREP_FBLK + PREP_XBLK, 256, 0, stream>>>(
      w, wfr, x, xbf, dr, dc, dd, cursor, elist);
  spiral_gemm<<<NWG2, 64, 0, stream>>>(xbf, wfr, bias, sp, hbf);
  pool_rows<<<VOUT_, 256, 0, stream>>>(hbf, cursor, elist, out);
}

// Round 12
// 154.348 us; speedup vs baseline: 1.9587x; 1.3054x over previous
//
#include <hip/hip_runtime.h>

#define B_    8
#define V_    50000
#define KNB   9
#define CIN_  64
#define COUT_ 128
#define VOUT_ 12500
#define NNZ_  37500
#define KTOT  576      // KNB*CIN_
#define M_    400000   // B_*V_
#define NWG   3125     // M_/128

typedef short bf16x8 __attribute__((ext_vector_type(8)));
typedef float f32x4  __attribute__((ext_vector_type(4)));

#define AS1 __attribute__((address_space(1)))
#define AS3 __attribute__((address_space(3)))

__device__ __forceinline__ unsigned short f2bf(float f) {
  unsigned u = __float_as_uint(f);
  u += 0x7fffu + ((u >> 16) & 1u);          // RNE
  return (unsigned short)(u >> 16);
}
__device__ __forceinline__ unsigned pack2(float lo, float hi) {
  return (unsigned)f2bf(lo) | ((unsigned)f2bf(hi) << 16);
}
__device__ __forceinline__ float bf2f(unsigned short u) {
  return __uint_as_float((unsigned)u << 16);
}

__device__ __forceinline__ void gld_lds16(const void* g, void* l) {
  __builtin_amdgcn_global_load_lds((const AS1 unsigned*)g, (AS3 unsigned*)l, 16, 0, 0);
}

// Fused prep: [0,36) W->frag-major bf16; [36,183) pool bucket-fill; [183,2231)
// convert x fp32->bf16 (grid-stride).
#define PREP_WBLK 36
#define PREP_FBLK 147
#define PREP_XBLK 2048
__global__ __launch_bounds__(256) void prep(const float* __restrict__ w,
                                            unsigned short* __restrict__ wfr,
                                            const float* __restrict__ x,
                                            unsigned short* __restrict__ xbf,
                                            const int* __restrict__ dr,
                                            const int* __restrict__ dc,
                                            const float* __restrict__ dd,
                                            int* __restrict__ cursor,
                                            int2* __restrict__ elist) {
  const int bid = blockIdx.x;
  if (bid < PREP_WBLK) {
    // W -> MFMA-fragment-major: chunk i holds, for lane=i&63, n=(i>>6)&3,
    // wc=(i>>8)&1, ks=(i>>9)&1, t=i>>10:
    //   W[col=wc*64+n*16+(lane&15)][k=t*64+ks*32+(lane>>4)*8 .. +8]
    int i = bid * 256 + threadIdx.x;        // 0..9215
    int lane = i & 63, n = (i >> 6) & 3, wc = (i >> 8) & 1, ks = (i >> 9) & 1, t = i >> 10;
    int col = wc * 64 + n * 16 + (lane & 15);
    int k0 = t * 64 + ks * 32 + (lane >> 4) * 8;
    const float* src = w + (size_t)col * KTOT + k0;
    float4 f0 = reinterpret_cast<const float4*>(src)[0];
    float4 f1 = reinterpret_cast<const float4*>(src)[1];
    uint4 o;
    o.x = pack2(f0.x, f0.y);
    o.y = pack2(f0.z, f0.w);
    o.z = pack2(f1.x, f1.y);
    o.w = pack2(f1.z, f1.w);
    reinterpret_cast<uint4*>(wfr)[i] = o;
  } else if (bid < PREP_WBLK + PREP_FBLK) {
    int e = (bid - PREP_WBLK) * 256 + threadIdx.x;
    if (e < NNZ_) {
      int r = dr[e];
      int slot = atomicAdd(&cursor[r], 1);
      if (slot < 32) elist[r * 32 + slot] = make_int2(dc[e], __float_as_int(dd[e]));
    }
  } else {
    const int nq = B_ * V_ * CIN_ / 4;      // 6.4M float4 quads
    for (int q = (bid - PREP_WBLK - PREP_FBLK) * 256 + threadIdx.x; q < nq;
         q += PREP_XBLK * 256) {
      float4 f = reinterpret_cast<const float4*>(x)[q];
      ushort4 o;
      o.x = f2bf(f.x); o.y = f2bf(f.y); o.z = f2bf(f.z); o.w = f2bf(f.w);
      reinterpret_cast<ushort4*>(xbf)[q] = o;
    }
  }
}

// h = elu(gather(x) @ W^T + bias). 128x128 tile, 4 waves, BK=64. (R9 structure,
// restored after R10/R11 refutations, with two fixes:)
//  FIX 1 (residency): spc as USHORT (idx<50000<65536): struct = 49152+2304 =
//    51456B -> 3 blocks/CU (R9's 53760B was 304B over the 2.97-block threshold).
//  FIX 2 (vmcnt race): A(t) staged at iter t-2; ops issued after it at entry of
//    iter t = B(t)x8 + A(t+1)x4 = 12 -> vmcnt(12) (t=0: 4, t=8: 8). R9's
//    vmcnt(16) against a 16-deep queue was a no-op.
// Pipeline: A 3 LDS buffers (2-deep), B double-banked registers (1-deep),
// one raw s_barrier per K-step, wait BEFORE barrier, lgkmcnt(0) at iter end
// (protects WAR on the A-buffer being re-staged next iter).
struct GemmSM { char A[3][16384]; unsigned short spc[1152]; };

__global__ __launch_bounds__(256, 3) void spiral_gemm(
    const unsigned short* __restrict__ xbf, const unsigned short* __restrict__ wfr,
    const float* __restrict__ bias, const int* __restrict__ sp,
    unsigned short* __restrict__ hbf)
{
  __shared__ GemmSM smv;
  GemmSM* sm = &smv;

  // ---- bijective XCD swizzle (nwg=3125: q=390, r=5)
  const int q_ = NWG / 8, r_ = NWG % 8;
  const int xcd = blockIdx.x & 7, pos = blockIdx.x >> 3;
  const int nbid = (xcd < r_) ? xcd * (q_ + 1) + pos
                              : r_ * (q_ + 1) + (xcd - r_) * q_ + pos;

  const int tid  = threadIdx.x;
  const int m0   = nbid * 128;
  const int wave = tid >> 6;
  const int lane = tid & 63;

  // ---- cache all 1152 spiral indices (ushort) for this tile in LDS
  for (int i = tid; i < 128 * KNB; i += 256) {
    int row = i / KNB, j = i - row * KNB;
    int m = m0 + row;
    int b = m / V_;
    int v = m - b * V_;
    sm->spc[i] = (unsigned short)sp[v * KNB + j];
  }

  // ---- staging geometry: 4 rounds x 32 rows, 8 lanes x 16B chunks per 128B row
  const int rrow  = tid >> 3;                       // 0..31
  const int chunkoff = (((tid & 7) ^ (rrow & 7)) << 4); // inverse-swizzled source chunk
  unsigned boff[4];
  int sbase[4], ldso[4];
  #pragma unroll
  for (int r = 0; r < 4; ++r) {
    int row = r * 32 + rrow;
    int m = m0 + row;
    int b = m / V_;
    boff[r]  = (unsigned)b * (V_ * CIN_ * 2);       // byte offset of batch slice
    sbase[r] = row * KNB;
    ldso[r]  = (r * 32 + wave * 8) * 128;
  }

  // ---- compute geometry
  const int wr = wave >> 1, wc = wave & 1;
  const int lr = lane & 15, lg = lane >> 4;
  const bf16x8* wbase = (const bf16x8*)wfr + wc * 256 + lane;   // +((t*2+ks)*512 + n*64)

  f32x4 acc[4][4];
  #pragma unroll
  for (int i = 0; i < 4; ++i)
    #pragma unroll
    for (int j = 0; j < 4; ++j)
      acc[i][j] = (f32x4){0.f, 0.f, 0.f, 0.f};

  auto stageA = [&](int bi, int t) {
    char* Ab = sm->A[bi];
    #pragma unroll
    for (int r = 0; r < 4; ++r) {
      unsigned idx = sm->spc[sbase[r] + t];         // LDS read (lgkm domain)
      unsigned off = boff[r] + idx * 128u + (unsigned)chunkoff;
      gld_lds16((const char*)xbf + off, Ab + ldso[r]);
    }
  };

  bf16x8 b0[2][4], b1[2][4];
  auto loadB = [&](bf16x8 (&bk)[2][4], int t) {
    #pragma unroll
    for (int ks = 0; ks < 2; ++ks)
      #pragma unroll
      for (int n = 0; n < 4; ++n)
        bk[ks][n] = wbase[(t * 2 + ks) * 512 + n * 64];
  };

  // ---- prologue (spc visible to all; then B(0)x8, A(0)x4, A(1)x4)
  __syncthreads();
  loadB(b0, 0);
  stageA(0, 0);
  stageA(1, 1);

#define GITER(T, BC, BN)                                                        \
  do {                                                                          \
    asm volatile("s_waitcnt vmcnt(%0)"                                          \
                 :: "i"((T) == 0 ? 4 : ((T) <= 7 ? 12 : 8)) : "memory");        \
    __builtin_amdgcn_sched_barrier(0);                                          \
    __builtin_amdgcn_s_barrier();                                               \
    if ((T) + 1 < KNB) loadB(BN, (T) + 1);                                      \
    __builtin_amdgcn_sched_barrier(0);                                          \
    if ((T) + 2 < KNB) stageA(((T) + 2) % 3, (T) + 2);                          \
    __builtin_amdgcn_sched_barrier(0);                                          \
    {                                                                           \
      const char* Ab = sm->A[(T) % 3];                                          \
      _Pragma("unroll")                                                         \
      for (int ks = 0; ks < 2; ++ks) {                                          \
        const int kb = ks * 64 + lg * 16;                                       \
        bf16x8 af[4];                                                           \
        _Pragma("unroll")                                                       \
        for (int m = 0; m < 4; ++m) {                                           \
          int row = wr * 64 + m * 16 + lr;                                      \
          af[m] = *reinterpret_cast<const bf16x8*>(                             \
              Ab + row * 128 + (kb ^ ((row & 7) << 4)));                        \
        }                                                                       \
        __builtin_amdgcn_s_setprio(1);                                          \
        _Pragma("unroll")                                                       \
        for (int m = 0; m < 4; ++m)                                             \
          _Pragma("unroll")                                                     \
          for (int n = 0; n < 4; ++n)                                           \
            acc[m][n] = __builtin_amdgcn_mfma_f32_16x16x32_bf16(                \
                af[m], BC[ks][n], acc[m][n], 0, 0, 0);                          \
        __builtin_amdgcn_s_setprio(0);                                          \
      }                                                                         \
    }                                                                           \
    asm volatile("s_waitcnt lgkmcnt(0)" ::: "memory");                          \
    __builtin_amdgcn_sched_barrier(0);                                          \
  } while (0)

  GITER(0, b0, b1);
  GITER(1, b1, b0);
  GITER(2, b0, b1);
  GITER(3, b1, b0);
  GITER(4, b0, b1);
  GITER(5, b1, b0);
  GITER(6, b0, b1);
  GITER(7, b1, b0);
  GITER(8, b0, b1);
#undef GITER

  // ---- epilogue: bias + ELU -> bf16 into swizzled hs over A[0..1] (32KB),
  //      then coalesced 16B global stores.
  __syncthreads();
  char* hsb = (char*)sm;
  #pragma unroll
  for (int n = 0; n < 4; ++n) {
    const int c = wc * 64 + n * 16 + lr;
    const float bv = bias[c];
    #pragma unroll
    for (int m = 0; m < 4; ++m) {
      const int row0 = wr * 64 + m * 16 + lg * 4;
      #pragma unroll
      for (int j = 0; j < 4; ++j) {
        const int row = row0 + j;
        float vv = acc[m][n][j] + bv;
        vv = vv > 0.f ? vv : (__expf(vv) - 1.f);
        *reinterpret_cast<unsigned short*>(
            hsb + row * 256 + ((c * 2) ^ ((row & 7) << 4))) = f2bf(vv);
      }
    }
  }
  __syncthreads();
  const int r2 = tid >> 1, hf = tid & 1;
  uint4* drow = reinterpret_cast<uint4*>(hbf + (size_t)(m0 + r2) * COUT_ + hf * 64);
  #pragma unroll
  for (int u = 0; u < 8; ++u) {
    int cb = hf * 128 + u * 16;
    drow[u] = *reinterpret_cast<const uint4*>(hsb + r2 * 256 + (cb ^ ((r2 & 7) << 4)));
  }
}

// One block per output row; 8 b-groups x 32 lanes; bucketed entries (cap 32).
__global__ __launch_bounds__(256) void pool_rows(const unsigned short* __restrict__ hbf,
                                                 const int* __restrict__ cursor,
                                                 const int2* __restrict__ elist,
                                                 float* __restrict__ out) {
  const int row = blockIdx.x;
  const int bg = threadIdx.x >> 5;     // batch 0..7
  const int lc = threadIdx.x & 31;     // c-quad 0..31
  int cnt = cursor[row];
  cnt = cnt < 32 ? cnt : 32;
  const unsigned short* hb = hbf + (size_t)bg * (V_ * COUT_) + lc * 4;
  float4 acc = {0.f, 0.f, 0.f, 0.f};
  for (int e = 0; e < cnt; ++e) {
    int2 en = elist[row * 32 + e];
    float d = __int_as_float(en.y);
    ushort4 v = *reinterpret_cast<const ushort4*>(hb + (size_t)en.x * COUT_);
    acc.x += d * bf2f(v.x);
    acc.y += d * bf2f(v.y);
    acc.z += d * bf2f(v.z);
    acc.w += d * bf2f(v.w);
  }
  *reinterpret_cast<float4*>(out + ((size_t)bg * VOUT_ + row) * COUT_ + lc * 4) = acc;
}

extern "C" void kernel_launch(void* const* d_in, const int* in_sizes, int n_in,
                              void* d_out, int out_size, void* d_ws, size_t ws_size,
                              hipStream_t stream) {
  const float* x    = (const float*)d_in[0];
  const float* w    = (const float*)d_in[1];
  const float* bias = (const float*)d_in[2];
  const int*   sp   = (const int*)d_in[3];
  const int*   dr   = (const int*)d_in[4];
  const int*   dc   = (const int*)d_in[5];
  const float* dd   = (const float*)d_in[6];
  float* out = (float*)d_out;

  char* ws = (char*)d_ws;
  unsigned short* wfr = (unsigned short*)ws;                       // 147,456 B (frag-major)
  unsigned short* xbf = (unsigned short*)(ws + 147456);            // 51,200,000 B
  unsigned short* hbf = (unsigned short*)(ws + 51347456);          // 102,400,000 B
  int*  cursor  = (int*) (ws + 153747456);                         // 50,000 B
  int2* elist   = (int2*)(ws + 153797456);                         // 3,200,000 B

  hipMemsetAsync(cursor, 0, VOUT_ * sizeof(int), stream);
  prep<<<PREP_WBLK + PREP_FBLK + PREP_XBLK, 256, 0, stream>>>(
      w, wfr, x, xbf, dr, dc, dd, cursor, elist);
  spiral_gemm<<<NWG, 256, 0, stream>>>(xbf, wfr, bias, sp, hbf);
  pool_rows<<<VOUT_, 256, 0, stream>>>(hbf, cursor, elist, out);
}